// Round 23
// baseline (36.601 us; speedup 1.0000x reference)
//
#include <hip/hip_runtime.h>

#define L_SEQ 4096
#define BATCH 2
#define NHEAD 4
#define DHEAD 32
#define DMODEL 128

typedef __attribute__((ext_vector_type(4))) float floatx4;
typedef __attribute__((ext_vector_type(16))) float floatx16;
typedef __attribute__((ext_vector_type(8))) __bf16 bf16x8;
typedef __attribute__((ext_vector_type(8))) unsigned short ushort8;
typedef __attribute__((ext_vector_type(4))) unsigned int uintx4;

__device__ __forceinline__ floatx4 MFMA(ushort8 a, ushort8 b, floatx4 c) {
  return __builtin_amdgcn_mfma_f32_16x16x32_bf16(
      __builtin_bit_cast(bf16x8, a), __builtin_bit_cast(bf16x8, b), c, 0, 0, 0);
}
__device__ __forceinline__ floatx16 MFMA32(ushort8 a, ushort8 b, floatx16 c) {
  return __builtin_amdgcn_mfma_f32_32x32x16_bf16(
      __builtin_bit_cast(bf16x8, a), __builtin_bit_cast(bf16x8, b), c, 0, 0, 0);
}

__device__ __forceinline__ unsigned short f2bf(float f) {
  union { float f; unsigned int u; } x; x.f = f;
  unsigned int u = x.u + 0x7fffu + ((x.u >> 16) & 1u);   // RNE truncate
  return (unsigned short)(u >> 16);
}

__device__ __forceinline__ unsigned pkbf(float lo, float hi) {
  unsigned r;
  asm("v_cvt_pk_bf16_f32 %0, %1, %2" : "=v"(r) : "v"(lo), "v"(hi));
  return r;
}

// ---------------------------------------------------------------------------
// Kernel 1: fused QKV projection. (FROZEN - byte-identical to green R22)
// ---------------------------------------------------------------------------
#define WLDS 136

__global__ __launch_bounds__(256) void proj_kernel(
    const float* __restrict__ xq, const float* __restrict__ xk,
    const float* __restrict__ xv,
    const float* __restrict__ WQ, const float* __restrict__ bQ,
    const float* __restrict__ WK, const float* __restrict__ bK,
    const float* __restrict__ WV, const float* __restrict__ bV,
    unsigned short* __restrict__ Qs, unsigned short* __restrict__ Ks,
    unsigned short* __restrict__ Vt)
{
  __shared__ unsigned short Wl[128 * WLDS];
  __shared__ unsigned short Xl[64 * WLDS];
  __shared__ float bl[128];
  const int mat = blockIdx.z;
  const int b   = blockIdx.y;
  const int l0  = blockIdx.x * 64;
  const int t   = blockIdx.x;               // kv tile index (l0 / 64)
  const float* __restrict__ x    = (mat == 0) ? xq : (mat == 1) ? xk : xv;
  const float* __restrict__ W    = (mat == 0) ? WQ : (mat == 1) ? WK : WV;
  const float* __restrict__ bias = (mat == 0) ? bQ : (mat == 1) ? bK : bV;
  const int tid = threadIdx.x;

  // stage W (128 rows) - coalesced float4
  #pragma unroll
  for (int it = 0; it < 16; ++it) {
    int idx = tid + it * 256;
    int row = idx >> 5;
    int col = (idx & 31) * 4;
    floatx4 v = *(const floatx4*)(W + row * 128 + col);
    unsigned short* dst = Wl + row * WLDS + col;
    dst[0] = f2bf(v[0]); dst[1] = f2bf(v[1]);
    dst[2] = f2bf(v[2]); dst[3] = f2bf(v[3]);
  }
  // stage x tile (64 rows of this batch) - coalesced float4 per row segment
  #pragma unroll
  for (int it = 0; it < 8; ++it) {
    int idx = tid + it * 256;
    int row = idx >> 5;
    int col = (idx & 31) * 4;
    floatx4 v = *(const floatx4*)(x + ((size_t)(l0 + row) * BATCH + b) * DMODEL + col);
    unsigned short* dst = Xl + row * WLDS + col;
    dst[0] = f2bf(v[0]); dst[1] = f2bf(v[1]);
    dst[2] = f2bf(v[2]); dst[3] = f2bf(v[3]);
  }
  if (tid < 128) bl[tid] = bias[tid];
  __syncthreads();

  const int w = tid >> 6, lane = tid & 63;
  const int g = lane >> 4, qi = lane & 15;

  ushort8 xf[4];
  #pragma unroll
  for (int kk = 0; kk < 4; ++kk)
    xf[kk] = *(const ushort8*)(Xl + (w * 16 + qi) * WLDS + kk * 32 + g * 8);

  floatx4 acc[8];
  #pragma unroll
  for (int n = 0; n < 8; ++n) acc[n] = (floatx4){0.f, 0.f, 0.f, 0.f};

  #pragma unroll
  for (int kk = 0; kk < 4; ++kk) {
    #pragma unroll
    for (int n = 0; n < 8; ++n) {
      ushort8 wf = *(const ushort8*)(Wl + (n * 16 + qi) * WLDS + kk * 32 + g * 8);
      acc[n] = (mat == 2) ? MFMA(wf, xf[kk], acc[n]) : MFMA(xf[kk], wf, acc[n]);
    }
  }

  // ---- epilogue: acc -> natural [row][ch] bf16 tile in LDS (reuse Xl) ----
  __syncthreads();   // all Xl fragment reads complete before overwrite
  if (mat != 2) {
    // acc[n][r] = D[row = w*16+4g+r][ch = n*16+qi]
    const float scale = (mat == 0) ? 0.25503486f : 1.0f;  // Q: log2(e)/sqrt(32)
    #pragma unroll
    for (int n = 0; n < 8; ++n) {
      int c = n * 16 + qi;
      float bb = bl[c];
      #pragma unroll
      for (int r = 0; r < 4; ++r) {
        int row = w * 16 + 4 * g + r;
        Xl[row * WLDS + c] = f2bf((acc[n][r] + bb) * scale);
      }
    }
  } else {
    // V transposed MFMA: acc[n][r] = D[ch = n*16+4g+r][row = w*16+qi]
    #pragma unroll
    for (int n = 0; n < 8; ++n) {
      #pragma unroll
      for (int r = 0; r < 4; ++r) {
        int c = n * 16 + 4 * g + r;
        int row = w * 16 + qi;
        Xl[row * WLDS + c] = f2bf(acc[n][r] + bl[c]);
      }
    }
  }
  __syncthreads();

  // ---- cooperative fully-coalesced stores ----
  const int hb4 = b * NHEAD;
  if (mat == 0) {
    // Q natural [plane][l0+row][32]: item = (row, h, ch8)
    #pragma unroll
    for (int it = 0; it < 4; ++it) {
      int idx = tid + it * 256;            // 0..1023
      int row = idx >> 4;                  // 0..63
      int h   = (idx >> 2) & 3;
      int ch  = idx & 3;
      ushort8 vv = *(const ushort8*)(Xl + row * WLDS + h * 32 + ch * 8);
      *(ushort8*)(Qs + ((size_t)(hb4 + h) * L_SEQ + l0 + row) * DHEAD + ch * 8) = vv;
    }
  } else if (mat == 1) {
    // K frag-packed
    #pragma unroll
    for (int it = 0; it < 4; ++it) {
      int idx = tid + it * 256;            // 0..1023
      int h   = idx >> 8;
      int jf  = (idx >> 6) & 3;
      int L   = idx & 63;
      int rhi = jf >> 1, dj = jf & 1;
      int hi2 = L >> 5, ql2 = L & 31;
      ushort8 vv = *(const ushort8*)(Xl + (rhi * 32 + ql2) * WLDS
                                     + h * 32 + dj * 16 + hi2 * 8);
      *(ushort8*)(Ks + ((((size_t)(hb4 + h) * 64 + t) * 4 + jf) * 64 + L) * 8) = vv;
    }
  } else {
    // V frag-packed
    #pragma unroll
    for (int it = 0; it < 4; ++it) {
      int idx = tid + it * 256;            // 0..1023
      int h   = idx >> 8;
      int s   = (idx >> 6) & 3;
      int L   = idx & 63;
      int hi2 = L >> 5, dh2 = L & 31;
      ushort8 vv;
      #pragma unroll
      for (int u = 0; u < 8; ++u) {
        int kvt = 16 * s + 8 * (u >> 2) + 4 * hi2 + (u & 3);
        vv[u] = Xl[kvt * WLDS + h * 32 + dh2];
      }
      *(ushort8*)(Vt + ((((size_t)(hb4 + h) * 64 + t) * 4 + s) * 64 + L) * 8) = vv;
    }
  }
}

// ---------------------------------------------------------------------------
// Kernel 2: KV-split flash attention, 32x32 MFMA. (FROZEN - byte-identical
// to the thrice-verified green R18/R20/R22 kernel.)
// ---------------------------------------------------------------------------
#define MFIX 17.3123405f   // 12 * log2(e)

__global__ __launch_bounds__(256, 4) void attn_kernel(
    const unsigned short* __restrict__ Qs, const unsigned short* __restrict__ Ks,
    const unsigned short* __restrict__ Vt,
    float* __restrict__ Opart, float* __restrict__ MLpart)
{
  __shared__ float Tr[4][32 * 36];   // per-wave transpose scratch

  const int tid = threadIdx.x;
  const int w = tid >> 6, lane = tid & 63;
  const int ql = lane & 31, hi = lane >> 5;

  const int ph    = blockIdx.x;              // 0..15
  const int plane = ph >> 1;
  const int half  = ph & 1;
  const int j     = blockIdx.y;              // 0..63
  const int bq    = j & 15, mq = j >> 4;
  const int tq    = (mq == 0) ? bq : (mq == 1) ? 63 - bq
                  : (mq == 2) ? 16 + bq : 47 - bq;

  const int c     = w;                       // chunk index = wave id
  const int width = (tq >> 2) + 1;           // ceil((tq+1)/4)
  const int t0    = c * width;
  const int tend  = min(t0 + width, tq + 1); // may be <= t0 (empty)

  const unsigned short* __restrict__ Qh = Qs + (size_t)plane * L_SEQ * DHEAD;

  const int q0 = tq * 64 + half * 32;
  // Q B-frags: lane holds Q[q0+ql][dhalf*16 + hi*8 + 0..7]
  ushort8 qf0 = *(const ushort8*)(Qh + (size_t)(q0 + ql) * DHEAD + hi * 8);
  ushort8 qf1 = *(const ushort8*)(Qh + (size_t)(q0 + ql) * DHEAD + 16 + hi * 8);

  const floatx16 z16 = {0,0,0,0,0,0,0,0,0,0,0,0,0,0,0,0};
  floatx16 acc_a = z16, acc_b = z16;  // O^T split over kv sub-ranges
  float l = 0.f;

  // fragment-packed tile base pointers (advance 2048 ush per tile)
  const unsigned short* kb = Ks + ((size_t)plane * 64 + t0) * 2048 + (size_t)lane * 8;
  const unsigned short* vb = Vt + ((size_t)plane * 64 + t0) * 2048 + (size_t)lane * 8;

  #pragma unroll 2
  for (int t = t0; t < tend; ++t) {
    // ---- loads: 8 x fully-coalesced 16B/lane ----
    ushort8 kf00 = *(const ushort8*)(kb);           // j0: rows 0-31,  d 0..15
    ushort8 kf01 = *(const ushort8*)(kb + 512);     // j1: rows 0-31,  d 16..31
    ushort8 kf10 = *(const ushort8*)(kb + 1024);    // j2: rows 32-63, d 0..15
    ushort8 kf11 = *(const ushort8*)(kb + 1536);    // j3: rows 32-63, d 16..31
    ushort8 va0  = *(const ushort8*)(vb);           // s0: kv 0..15
    ushort8 va1  = *(const ushort8*)(vb + 512);     // s1: kv 16..31
    ushort8 va2  = *(const ushort8*)(vb + 1024);    // s2: kv 32..47
    ushort8 va3  = *(const ushort8*)(vb + 1536);    // s3: kv 48..63
    kb += 2048;
    vb += 2048;

    // ---- QK^T: St[kg][row kv'=(r&3)+8*(r>>2)+4*hi][col q=ql] ----
    __builtin_amdgcn_s_setprio(1);
    floatx16 St0 = MFMA32(kf00, qf0, z16);
    St0 = MFMA32(kf01, qf1, St0);
    floatx16 St1 = MFMA32(kf10, qf0, z16);
    St1 = MFMA32(kf11, qf1, St1);
    __builtin_amdgcn_s_setprio(0);

    // ---- fixed-m softmax in exp2 domain: P = 2^(S - MFIX) ----
    float rs0 = 0.f, rs1 = 0.f, rs2 = 0.f, rs3 = 0.f;
    #pragma unroll
    for (int i = 0; i < 8; ++i)  { float e = __builtin_amdgcn_exp2f(St0[i] - MFIX); St0[i] = e; rs0 += e; }
    #pragma unroll
    for (int i = 8; i < 16; ++i) { float e = __builtin_amdgcn_exp2f(St0[i] - MFIX); St0[i] = e; rs1 += e; }
    #pragma unroll
    for (int i = 0; i < 8; ++i)  { float e = __builtin_amdgcn_exp2f(St1[i] - MFIX); St1[i] = e; rs2 += e; }
    #pragma unroll
    for (int i = 8; i < 16; ++i) { float e = __builtin_amdgcn_exp2f(St1[i] - MFIX); St1[i] = e; rs3 += e; }
    l += (rs0 + rs1) + (rs2 + rs3);

    // ---- pack P; PV with dual accumulators (2 independent MFMA chains) ----
    uintx4 pb0, pb1;
    pb0[0] = pkbf(St0[0], St0[1]); pb0[1] = pkbf(St0[2], St0[3]);
    pb0[2] = pkbf(St0[4], St0[5]); pb0[3] = pkbf(St0[6], St0[7]);
    pb1[0] = pkbf(St0[8], St0[9]);  pb1[1] = pkbf(St0[10], St0[11]);
    pb1[2] = pkbf(St0[12], St0[13]); pb1[3] = pkbf(St0[14], St0[15]);
    __builtin_amdgcn_s_setprio(1);
    acc_a = MFMA32(va0, __builtin_bit_cast(ushort8, pb0), acc_a);
    acc_a = MFMA32(va1, __builtin_bit_cast(ushort8, pb1), acc_a);
    __builtin_amdgcn_s_setprio(0);
    pb0[0] = pkbf(St1[0], St1[1]); pb0[1] = pkbf(St1[2], St1[3]);
    pb0[2] = pkbf(St1[4], St1[5]); pb0[3] = pkbf(St1[6], St1[7]);
    pb1[0] = pkbf(St1[8], St1[9]);  pb1[1] = pkbf(St1[10], St1[11]);
    pb1[2] = pkbf(St1[12], St1[13]); pb1[3] = pkbf(St1[14], St1[15]);
    __builtin_amdgcn_s_setprio(1);
    acc_b = MFMA32(va2, __builtin_bit_cast(ushort8, pb0), acc_b);
    acc_b = MFMA32(va3, __builtin_bit_cast(ushort8, pb1), acc_b);
    __builtin_amdgcn_s_setprio(0);
  }

  // ---- combine kv sub-range partial sums (lanes ql / ql+32, same q col) ----
  l += __shfl_xor(l, 32);

  // ---- epilogue: transpose O^T -> O via LDS, write f32 partials ----
  const int slot = ((plane * 64 + tq) * 4 + c);
  float* T = &Tr[w][0];
  #pragma unroll
  for (int r = 0; r < 16; ++r) {
    int dh = (r & 3) + 8 * (r >> 2) + 4 * hi;
    T[ql * 36 + dh] = acc_a[r] + acc_b[r];
  }
  asm volatile("s_waitcnt lgkmcnt(0)" ::: "memory");
  __builtin_amdgcn_sched_barrier(0);

  const int qr = lane >> 1, dg = (lane & 1) * 16;
  float* __restrict__ Op = Opart + (size_t)slot * 2048 + half * 32 * 32;
  #pragma unroll
  for (int j2 = 0; j2 < 4; ++j2) {
    floatx4 vv = *(const floatx4*)(T + qr * 36 + dg + 4 * j2);
    *(floatx4*)(Op + qr * 32 + dg + 4 * j2) = vv;
  }
  if (hi == 0) {
    MLpart[(size_t)slot * 128 + (half * 32 + ql) * 2 + 0] = MFIX;
    MLpart[(size_t)slot * 128 + (half * 32 + ql) * 2 + 1] = l;
  }
}

// ---------------------------------------------------------------------------
// Kernel 3 (R23): combine + output projection, dedup'd combine.
// Grid (256, 1): block = 32 output rows x ALL 128 cols. Each output row is
// combined exactly once (was twice in the (128,2) col-split). W stages all
// 128 rows; 512 blocks = 2/CU.
//   m0 = blockIdx.x*32; b = m0>>12; tq = (m0>>6)&63; rhalf = (m0>>5)&1.
// Combine thread = (q2 = tid>>3 in 0..31, dg8 = tid&7): 4 ch per head.
// Matmul: wave w -> row-tile (w&1), col-base (w>>1)*64, 4 col-tiles each.
// ---------------------------------------------------------------------------
__global__ __launch_bounds__(256) void oproj_fused_kernel(
    const float* __restrict__ Opart, const float* __restrict__ MLpart,
    const float* __restrict__ WO, const float* __restrict__ bO,
    float* __restrict__ out)
{
  __shared__ unsigned short Cl[32 * WLDS];   // combined ctx tile (32 rows), bf16
  __shared__ unsigned short Wl[128 * WLDS];
  __shared__ float bl[128];
  const int m0    = blockIdx.x * 32;
  const int b     = m0 >> 12;                // 4096 rows per batch
  const int tq    = (m0 >> 6) & 63;
  const int rhalf = (m0 >> 5) & 1;
  const int tid = threadIdx.x;

  // --- stage all 128 W rows (bf16) ---
  #pragma unroll
  for (int it = 0; it < 16; ++it) {
    int idx = tid + it * 256;
    int row = idx >> 5, col = (idx & 31) * 4;
    floatx4 v = *(const floatx4*)(WO + (size_t)row * 128 + col);
    unsigned short* dst = Wl + row * WLDS + col;
    dst[0] = f2bf(v[0]); dst[1] = f2bf(v[1]);
    dst[2] = f2bf(v[2]); dst[3] = f2bf(v[3]);
  }
  if (tid < 128) bl[tid] = bO[tid];

  // --- combine phase: thread = (q2 = tid>>3, dg8 = tid&7) ---
  {
    const int q2  = tid >> 3;            // 0..31 local row
    const int dg8 = tid & 7;             // 0..7 -> 4 ch at dg8*4
    const int q   = rhalf * 32 + q2;     // row within the 64-row tq tile
    #pragma unroll
    for (int h = 0; h < 4; ++h) {
      const int slot0 = ((b * 4 + h) * 64 + tq) * 4;
      float mv[4], lv[4];
      float M = -1e30f;
      #pragma unroll
      for (int ci = 0; ci < 4; ++ci) {
        mv[ci] = MLpart[(size_t)(slot0 + ci) * 128 + q * 2 + 0];
        lv[ci] = MLpart[(size_t)(slot0 + ci) * 128 + q * 2 + 1];
        M = fmaxf(M, mv[ci]);
      }
      float Lsum = 0.f;
      float wgt[4];
      #pragma unroll
      for (int ci = 0; ci < 4; ++ci) {
        wgt[ci] = __expf(mv[ci] - M);
        Lsum += wgt[ci] * lv[ci];
      }
      float inv = 1.0f / Lsum;

      floatx4 a0 = (floatx4){0.f,0.f,0.f,0.f};
      #pragma unroll
      for (int ci = 0; ci < 4; ++ci) {
        const float* Op = Opart + (size_t)(slot0 + ci) * 2048 + q * 32 + dg8 * 4;
        floatx4 o0 = *(const floatx4*)(Op);
        a0 += wgt[ci] * o0;
      }
      unsigned short* dst = Cl + q2 * WLDS + h * 32 + dg8 * 4;
      #pragma unroll
      for (int j = 0; j < 4; ++j)
        dst[j] = f2bf(a0[j] * inv);
    }
  }
  __syncthreads();

  // --- matmul phase: 32 rows x 128 cols; wave w -> (row-tile w&1, cols (w>>1)*64) ---
  const int w = tid >> 6, lane = tid & 63;
  const int g = lane >> 4, qi = lane & 15;
  const int rt = w & 1;
  const int cb = (w >> 1) * 64;

  ushort8 xf[4];
  #pragma unroll
  for (int kk = 0; kk < 4; ++kk)
    xf[kk] = *(const ushort8*)(Cl + (rt * 16 + qi) * WLDS + kk * 32 + g * 8);

  floatx4 acc[4];
  #pragma unroll
  for (int n = 0; n < 4; ++n) acc[n] = (floatx4){0.f, 0.f, 0.f, 0.f};

  #pragma unroll
  for (int kk = 0; kk < 4; ++kk) {
    #pragma unroll
    for (int n = 0; n < 4; ++n) {
      ushort8 wf = *(const ushort8*)(Wl + (cb + n * 16 + qi) * WLDS + kk * 32 + g * 8);
      acc[n] = MFMA(xf[kk], wf, acc[n]);
    }
  }

  #pragma unroll
  for (int n = 0; n < 4; ++n) {
    int c = cb + n * 16 + qi;
    float bb = bl[c];
    #pragma unroll
    for (int r = 0; r < 4; ++r) {
      int mm = m0 + rt * 16 + 4 * g + r;
      out[(size_t)mm * DMODEL + c] = acc[n][r] + bb;
    }
  }
}

// ---------------------------------------------------------------------------
extern "C" void kernel_launch(void* const* d_in, const int* in_sizes, int n_in,
                              void* d_out, int out_size, void* d_ws, size_t ws_size,
                              hipStream_t stream) {
  const float* q  = (const float*)d_in[0];
  const float* k  = (const float*)d_in[1];
  const float* v  = (const float*)d_in[2];
  const float* WQ = (const float*)d_in[3];
  const float* bQ = (const float*)d_in[4];
  const float* WK = (const float*)d_in[5];
  const float* bK = (const float*)d_in[6];
  const float* WV = (const float*)d_in[7];
  const float* bV = (const float*)d_in[8];
  const float* WO = (const float*)d_in[9];
  const float* bO = (const float*)d_in[10];
  float* out = (float*)d_out;

  const size_t plane = (size_t)BATCH * NHEAD * L_SEQ * DHEAD;  // 1,048,576 ush
  unsigned short* Qs  = (unsigned short*)d_ws;
  unsigned short* Ks  = Qs + plane;
  unsigned short* Vt  = Ks + plane;
  unsigned short* ctx = Vt + plane;                 // kept in layout; unused
  float* Opart  = (float*)(ctx + plane);            // 2048 slots x 64 x 32 f32
  float* MLpart = Opart + (size_t)2048 * 2048;      // 2048 slots x 64 x 2 f32

  hipLaunchKernelGGL(proj_kernel, dim3(64, 2, 3), dim3(256), 0, stream,
                     q, k, v, WQ, bQ, WK, bK, WV, bV, Qs, Ks, Vt);
  hipLaunchKernelGGL(attn_kernel, dim3(16, 64), dim3(256), 0, stream,
                     Qs, Ks, Vt, Opart, MLpart);
  hipLaunchKernelGGL(oproj_fused_kernel, dim3(256), dim3(256), 0, stream,
                     Opart, MLpart, WO, bO, out);
}

// Round 24
// 36.299 us; speedup vs baseline: 1.0083x; 1.0083x over previous
//
#include <hip/hip_runtime.h>

#define L_SEQ 4096
#define BATCH 2
#define NHEAD 4
#define DHEAD 32
#define DMODEL 128

typedef __attribute__((ext_vector_type(4))) float floatx4;
typedef __attribute__((ext_vector_type(16))) float floatx16;
typedef __attribute__((ext_vector_type(8))) __bf16 bf16x8;
typedef __attribute__((ext_vector_type(8))) unsigned short ushort8;
typedef __attribute__((ext_vector_type(4))) unsigned int uintx4;

__device__ __forceinline__ floatx4 MFMA(ushort8 a, ushort8 b, floatx4 c) {
  return __builtin_amdgcn_mfma_f32_16x16x32_bf16(
      __builtin_bit_cast(bf16x8, a), __builtin_bit_cast(bf16x8, b), c, 0, 0, 0);
}
__device__ __forceinline__ floatx16 MFMA32(ushort8 a, ushort8 b, floatx16 c) {
  return __builtin_amdgcn_mfma_f32_32x32x16_bf16(
      __builtin_bit_cast(bf16x8, a), __builtin_bit_cast(bf16x8, b), c, 0, 0, 0);
}

__device__ __forceinline__ unsigned short f2bf(float f) {
  union { float f; unsigned int u; } x; x.f = f;
  unsigned int u = x.u + 0x7fffu + ((x.u >> 16) & 1u);   // RNE truncate
  return (unsigned short)(u >> 16);
}

__device__ __forceinline__ unsigned pkbf(float lo, float hi) {
  unsigned r;
  asm("v_cvt_pk_bf16_f32 %0, %1, %2" : "=v"(r) : "v"(lo), "v"(hi));
  return r;
}

// ---------------------------------------------------------------------------
// Kernel 1: fused QKV projection. (FROZEN - byte-identical to green R22)
// ---------------------------------------------------------------------------
#define WLDS 136

__global__ __launch_bounds__(256) void proj_kernel(
    const float* __restrict__ xq, const float* __restrict__ xk,
    const float* __restrict__ xv,
    const float* __restrict__ WQ, const float* __restrict__ bQ,
    const float* __restrict__ WK, const float* __restrict__ bK,
    const float* __restrict__ WV, const float* __restrict__ bV,
    unsigned short* __restrict__ Qs, unsigned short* __restrict__ Ks,
    unsigned short* __restrict__ Vt)
{
  __shared__ unsigned short Wl[128 * WLDS];
  __shared__ unsigned short Xl[64 * WLDS];
  __shared__ float bl[128];
  const int mat = blockIdx.z;
  const int b   = blockIdx.y;
  const int l0  = blockIdx.x * 64;
  const int t   = blockIdx.x;               // kv tile index (l0 / 64)
  const float* __restrict__ x    = (mat == 0) ? xq : (mat == 1) ? xk : xv;
  const float* __restrict__ W    = (mat == 0) ? WQ : (mat == 1) ? WK : WV;
  const float* __restrict__ bias = (mat == 0) ? bQ : (mat == 1) ? bK : bV;
  const int tid = threadIdx.x;

  // stage W (128 rows) - coalesced float4
  #pragma unroll
  for (int it = 0; it < 16; ++it) {
    int idx = tid + it * 256;
    int row = idx >> 5;
    int col = (idx & 31) * 4;
    floatx4 v = *(const floatx4*)(W + row * 128 + col);
    unsigned short* dst = Wl + row * WLDS + col;
    dst[0] = f2bf(v[0]); dst[1] = f2bf(v[1]);
    dst[2] = f2bf(v[2]); dst[3] = f2bf(v[3]);
  }
  // stage x tile (64 rows of this batch) - coalesced float4 per row segment
  #pragma unroll
  for (int it = 0; it < 8; ++it) {
    int idx = tid + it * 256;
    int row = idx >> 5;
    int col = (idx & 31) * 4;
    floatx4 v = *(const floatx4*)(x + ((size_t)(l0 + row) * BATCH + b) * DMODEL + col);
    unsigned short* dst = Xl + row * WLDS + col;
    dst[0] = f2bf(v[0]); dst[1] = f2bf(v[1]);
    dst[2] = f2bf(v[2]); dst[3] = f2bf(v[3]);
  }
  if (tid < 128) bl[tid] = bias[tid];
  __syncthreads();

  const int w = tid >> 6, lane = tid & 63;
  const int g = lane >> 4, qi = lane & 15;

  ushort8 xf[4];
  #pragma unroll
  for (int kk = 0; kk < 4; ++kk)
    xf[kk] = *(const ushort8*)(Xl + (w * 16 + qi) * WLDS + kk * 32 + g * 8);

  floatx4 acc[8];
  #pragma unroll
  for (int n = 0; n < 8; ++n) acc[n] = (floatx4){0.f, 0.f, 0.f, 0.f};

  #pragma unroll
  for (int kk = 0; kk < 4; ++kk) {
    #pragma unroll
    for (int n = 0; n < 8; ++n) {
      ushort8 wf = *(const ushort8*)(Wl + (n * 16 + qi) * WLDS + kk * 32 + g * 8);
      acc[n] = (mat == 2) ? MFMA(wf, xf[kk], acc[n]) : MFMA(xf[kk], wf, acc[n]);
    }
  }

  // ---- epilogue: acc -> natural [row][ch] bf16 tile in LDS (reuse Xl) ----
  __syncthreads();   // all Xl fragment reads complete before overwrite
  if (mat != 2) {
    // acc[n][r] = D[row = w*16+4g+r][ch = n*16+qi]
    const float scale = (mat == 0) ? 0.25503486f : 1.0f;  // Q: log2(e)/sqrt(32)
    #pragma unroll
    for (int n = 0; n < 8; ++n) {
      int c = n * 16 + qi;
      float bb = bl[c];
      #pragma unroll
      for (int r = 0; r < 4; ++r) {
        int row = w * 16 + 4 * g + r;
        Xl[row * WLDS + c] = f2bf((acc[n][r] + bb) * scale);
      }
    }
  } else {
    // V transposed MFMA: acc[n][r] = D[ch = n*16+4g+r][row = w*16+qi]
    #pragma unroll
    for (int n = 0; n < 8; ++n) {
      #pragma unroll
      for (int r = 0; r < 4; ++r) {
        int c = n * 16 + 4 * g + r;
        int row = w * 16 + qi;
        Xl[row * WLDS + c] = f2bf(acc[n][r] + bl[c]);
      }
    }
  }
  __syncthreads();

  // ---- cooperative fully-coalesced stores ----
  const int hb4 = b * NHEAD;
  if (mat == 0) {
    // Q natural [plane][l0+row][32]: item = (row, h, ch8)
    #pragma unroll
    for (int it = 0; it < 4; ++it) {
      int idx = tid + it * 256;            // 0..1023
      int row = idx >> 4;                  // 0..63
      int h   = (idx >> 2) & 3;
      int ch  = idx & 3;
      ushort8 vv = *(const ushort8*)(Xl + row * WLDS + h * 32 + ch * 8);
      *(ushort8*)(Qs + ((size_t)(hb4 + h) * L_SEQ + l0 + row) * DHEAD + ch * 8) = vv;
    }
  } else if (mat == 1) {
    // K frag-packed
    #pragma unroll
    for (int it = 0; it < 4; ++it) {
      int idx = tid + it * 256;            // 0..1023
      int h   = idx >> 8;
      int jf  = (idx >> 6) & 3;
      int L   = idx & 63;
      int rhi = jf >> 1, dj = jf & 1;
      int hi2 = L >> 5, ql2 = L & 31;
      ushort8 vv = *(const ushort8*)(Xl + (rhi * 32 + ql2) * WLDS
                                     + h * 32 + dj * 16 + hi2 * 8);
      *(ushort8*)(Ks + ((((size_t)(hb4 + h) * 64 + t) * 4 + jf) * 64 + L) * 8) = vv;
    }
  } else {
    // V frag-packed
    #pragma unroll
    for (int it = 0; it < 4; ++it) {
      int idx = tid + it * 256;            // 0..1023
      int h   = idx >> 8;
      int s   = (idx >> 6) & 3;
      int L   = idx & 63;
      int hi2 = L >> 5, dh2 = L & 31;
      ushort8 vv;
      #pragma unroll
      for (int u = 0; u < 8; ++u) {
        int kvt = 16 * s + 8 * (u >> 2) + 4 * hi2 + (u & 3);
        vv[u] = Xl[kvt * WLDS + h * 32 + dh2];
      }
      *(ushort8*)(Vt + ((((size_t)(hb4 + h) * 64 + t) * 4 + s) * 64 + L) * 8) = vv;
    }
  }
}

// ---------------------------------------------------------------------------
// Kernel 2: KV-split flash attention, 32x32 MFMA. (FROZEN - byte-identical
// to the thrice-verified green R18/R20/R22 kernel.)
// ---------------------------------------------------------------------------
#define MFIX 17.3123405f   // 12 * log2(e)

__global__ __launch_bounds__(256, 4) void attn_kernel(
    const unsigned short* __restrict__ Qs, const unsigned short* __restrict__ Ks,
    const unsigned short* __restrict__ Vt,
    float* __restrict__ Opart, float* __restrict__ MLpart)
{
  __shared__ float Tr[4][32 * 36];   // per-wave transpose scratch

  const int tid = threadIdx.x;
  const int w = tid >> 6, lane = tid & 63;
  const int ql = lane & 31, hi = lane >> 5;

  const int ph    = blockIdx.x;              // 0..15
  const int plane = ph >> 1;
  const int half  = ph & 1;
  const int j     = blockIdx.y;              // 0..63
  const int bq    = j & 15, mq = j >> 4;
  const int tq    = (mq == 0) ? bq : (mq == 1) ? 63 - bq
                  : (mq == 2) ? 16 + bq : 47 - bq;

  const int c     = w;                       // chunk index = wave id
  const int width = (tq >> 2) + 1;           // ceil((tq+1)/4)
  const int t0    = c * width;
  const int tend  = min(t0 + width, tq + 1); // may be <= t0 (empty)

  const unsigned short* __restrict__ Qh = Qs + (size_t)plane * L_SEQ * DHEAD;

  const int q0 = tq * 64 + half * 32;
  // Q B-frags: lane holds Q[q0+ql][dhalf*16 + hi*8 + 0..7]
  ushort8 qf0 = *(const ushort8*)(Qh + (size_t)(q0 + ql) * DHEAD + hi * 8);
  ushort8 qf1 = *(const ushort8*)(Qh + (size_t)(q0 + ql) * DHEAD + 16 + hi * 8);

  const floatx16 z16 = {0,0,0,0,0,0,0,0,0,0,0,0,0,0,0,0};
  floatx16 acc_a = z16, acc_b = z16;  // O^T split over kv sub-ranges
  float l = 0.f;

  // fragment-packed tile base pointers (advance 2048 ush per tile)
  const unsigned short* kb = Ks + ((size_t)plane * 64 + t0) * 2048 + (size_t)lane * 8;
  const unsigned short* vb = Vt + ((size_t)plane * 64 + t0) * 2048 + (size_t)lane * 8;

  #pragma unroll 2
  for (int t = t0; t < tend; ++t) {
    // ---- loads: 8 x fully-coalesced 16B/lane ----
    ushort8 kf00 = *(const ushort8*)(kb);           // j0: rows 0-31,  d 0..15
    ushort8 kf01 = *(const ushort8*)(kb + 512);     // j1: rows 0-31,  d 16..31
    ushort8 kf10 = *(const ushort8*)(kb + 1024);    // j2: rows 32-63, d 0..15
    ushort8 kf11 = *(const ushort8*)(kb + 1536);    // j3: rows 32-63, d 16..31
    ushort8 va0  = *(const ushort8*)(vb);           // s0: kv 0..15
    ushort8 va1  = *(const ushort8*)(vb + 512);     // s1: kv 16..31
    ushort8 va2  = *(const ushort8*)(vb + 1024);    // s2: kv 32..47
    ushort8 va3  = *(const ushort8*)(vb + 1536);    // s3: kv 48..63
    kb += 2048;
    vb += 2048;

    // ---- QK^T: St[kg][row kv'=(r&3)+8*(r>>2)+4*hi][col q=ql] ----
    __builtin_amdgcn_s_setprio(1);
    floatx16 St0 = MFMA32(kf00, qf0, z16);
    St0 = MFMA32(kf01, qf1, St0);
    floatx16 St1 = MFMA32(kf10, qf0, z16);
    St1 = MFMA32(kf11, qf1, St1);
    __builtin_amdgcn_s_setprio(0);

    // ---- fixed-m softmax in exp2 domain: P = 2^(S - MFIX) ----
    float rs0 = 0.f, rs1 = 0.f, rs2 = 0.f, rs3 = 0.f;
    #pragma unroll
    for (int i = 0; i < 8; ++i)  { float e = __builtin_amdgcn_exp2f(St0[i] - MFIX); St0[i] = e; rs0 += e; }
    #pragma unroll
    for (int i = 8; i < 16; ++i) { float e = __builtin_amdgcn_exp2f(St0[i] - MFIX); St0[i] = e; rs1 += e; }
    #pragma unroll
    for (int i = 0; i < 8; ++i)  { float e = __builtin_amdgcn_exp2f(St1[i] - MFIX); St1[i] = e; rs2 += e; }
    #pragma unroll
    for (int i = 8; i < 16; ++i) { float e = __builtin_amdgcn_exp2f(St1[i] - MFIX); St1[i] = e; rs3 += e; }
    l += (rs0 + rs1) + (rs2 + rs3);

    // ---- pack P; PV with dual accumulators (2 independent MFMA chains) ----
    uintx4 pb0, pb1;
    pb0[0] = pkbf(St0[0], St0[1]); pb0[1] = pkbf(St0[2], St0[3]);
    pb0[2] = pkbf(St0[4], St0[5]); pb0[3] = pkbf(St0[6], St0[7]);
    pb1[0] = pkbf(St0[8], St0[9]);  pb1[1] = pkbf(St0[10], St0[11]);
    pb1[2] = pkbf(St0[12], St0[13]); pb1[3] = pkbf(St0[14], St0[15]);
    __builtin_amdgcn_s_setprio(1);
    acc_a = MFMA32(va0, __builtin_bit_cast(ushort8, pb0), acc_a);
    acc_a = MFMA32(va1, __builtin_bit_cast(ushort8, pb1), acc_a);
    __builtin_amdgcn_s_setprio(0);
    pb0[0] = pkbf(St1[0], St1[1]); pb0[1] = pkbf(St1[2], St1[3]);
    pb0[2] = pkbf(St1[4], St1[5]); pb0[3] = pkbf(St1[6], St1[7]);
    pb1[0] = pkbf(St1[8], St1[9]);  pb1[1] = pkbf(St1[10], St1[11]);
    pb1[2] = pkbf(St1[12], St1[13]); pb1[3] = pkbf(St1[14], St1[15]);
    __builtin_amdgcn_s_setprio(1);
    acc_b = MFMA32(va2, __builtin_bit_cast(ushort8, pb0), acc_b);
    acc_b = MFMA32(va3, __builtin_bit_cast(ushort8, pb1), acc_b);
    __builtin_amdgcn_s_setprio(0);
  }

  // ---- combine kv sub-range partial sums (lanes ql / ql+32, same q col) ----
  l += __shfl_xor(l, 32);

  // ---- epilogue: transpose O^T -> O via LDS, write f32 partials ----
  const int slot = ((plane * 64 + tq) * 4 + c);
  float* T = &Tr[w][0];
  #pragma unroll
  for (int r = 0; r < 16; ++r) {
    int dh = (r & 3) + 8 * (r >> 2) + 4 * hi;
    T[ql * 36 + dh] = acc_a[r] + acc_b[r];
  }
  asm volatile("s_waitcnt lgkmcnt(0)" ::: "memory");
  __builtin_amdgcn_sched_barrier(0);

  const int qr = lane >> 1, dg = (lane & 1) * 16;
  float* __restrict__ Op = Opart + (size_t)slot * 2048 + half * 32 * 32;
  #pragma unroll
  for (int j2 = 0; j2 < 4; ++j2) {
    floatx4 vv = *(const floatx4*)(T + qr * 36 + dg + 4 * j2);
    *(floatx4*)(Op + qr * 32 + dg + 4 * j2) = vv;
  }
  if (hi == 0) {
    MLpart[(size_t)slot * 128 + (half * 32 + ql) * 2 + 0] = MFIX;
    MLpart[(size_t)slot * 128 + (half * 32 + ql) * 2 + 1] = l;
  }
}

// ---------------------------------------------------------------------------
// Kernel 3 (R24): combine + output projection, R22 geometry.
// All MLpart m-entries are the constant MFIX (attn publishes it always,
// empty chunks included, with l=0 and O=0) -> wgt == exp(0) == 1.0 exactly.
// So combine is a plain sum: Lsum = sum(lv), a = sum(Op). Bit-identical to
// R22's output; deletes the m-loads and exp/fmax chain.
// Grid (128, 2): x = row-tile (b = x>>6, tq = x&63), y = col-half.
// ---------------------------------------------------------------------------
__global__ __launch_bounds__(256) void oproj_fused_kernel(
    const float* __restrict__ Opart, const float* __restrict__ MLpart,
    const float* __restrict__ WO, const float* __restrict__ bO,
    float* __restrict__ out)
{
  __shared__ unsigned short Cl[64 * WLDS];   // combined ctx tile, bf16
  __shared__ unsigned short Wl[64 * WLDS];
  __shared__ float bl[64];
  const int m0 = blockIdx.x * 64;
  const int n0 = blockIdx.y * 64;
  const int b  = m0 >> 12;                   // 4096 rows per batch
  const int tq = (m0 >> 6) & 63;
  const int tid = threadIdx.x;

  // --- stage W rows n0..n0+63 (bf16) ---
  #pragma unroll
  for (int it = 0; it < 8; ++it) {
    int idx = tid + it * 256;
    int row = idx >> 5, col = (idx & 31) * 4;
    floatx4 v = *(const floatx4*)(WO + (size_t)(n0 + row) * 128 + col);
    unsigned short* dst = Wl + row * WLDS + col;
    dst[0] = f2bf(v[0]); dst[1] = f2bf(v[1]);
    dst[2] = f2bf(v[2]); dst[3] = f2bf(v[3]);
  }
  if (tid < 64) bl[tid] = bO[n0 + tid];

  // --- combine phase (wgt == 1 identically): thread = (q, dg) ---
  {
    const int q  = tid >> 2;
    const int dg = tid & 3;
    #pragma unroll
    for (int h = 0; h < 4; ++h) {
      const int slot0 = ((b * 4 + h) * 64 + tq) * 4;
      float Lsum = 0.f;
      #pragma unroll
      for (int ci = 0; ci < 4; ++ci)
        Lsum += MLpart[(size_t)(slot0 + ci) * 128 + q * 2 + 1];
      float inv = 1.0f / Lsum;

      floatx4 a0 = (floatx4){0.f,0.f,0.f,0.f}, a1 = (floatx4){0.f,0.f,0.f,0.f};
      #pragma unroll
      for (int ci = 0; ci < 4; ++ci) {
        const float* Op = Opart + (size_t)(slot0 + ci) * 2048 + q * 32 + dg * 8;
        floatx4 o0 = *(const floatx4*)(Op);
        floatx4 o1 = *(const floatx4*)(Op + 4);
        a0 += o0;
        a1 += o1;
      }
      unsigned short* dst = Cl + q * WLDS + h * 32 + dg * 8;
      #pragma unroll
      for (int j = 0; j < 4; ++j) {
        dst[j]     = f2bf(a0[j] * inv);
        dst[4 + j] = f2bf(a1[j] * inv);
      }
    }
  }
  __syncthreads();

  // --- matmul phase ---
  const int w = tid >> 6, lane = tid & 63;
  const int g = lane >> 4, qi = lane & 15;

  ushort8 xf[4];
  #pragma unroll
  for (int kk = 0; kk < 4; ++kk)
    xf[kk] = *(const ushort8*)(Cl + (w * 16 + qi) * WLDS + kk * 32 + g * 8);

  floatx4 acc[4];
  #pragma unroll
  for (int n = 0; n < 4; ++n) acc[n] = (floatx4){0.f, 0.f, 0.f, 0.f};

  #pragma unroll
  for (int kk = 0; kk < 4; ++kk) {
    #pragma unroll
    for (int n = 0; n < 4; ++n) {
      ushort8 wf = *(const ushort8*)(Wl + (n * 16 + qi) * WLDS + kk * 32 + g * 8);
      acc[n] = MFMA(xf[kk], wf, acc[n]);
    }
  }

  #pragma unroll
  for (int n = 0; n < 4; ++n) {
    int c = n * 16 + qi;              // 0..63 within this col-half
    float bb = bl[c];
    #pragma unroll
    for (int r = 0; r < 4; ++r) {
      int mm = m0 + w * 16 + 4 * g + r;
      out[(size_t)mm * DMODEL + n0 + c] = acc[n][r] + bb;
    }
  }
}

// ---------------------------------------------------------------------------
extern "C" void kernel_launch(void* const* d_in, const int* in_sizes, int n_in,
                              void* d_out, int out_size, void* d_ws, size_t ws_size,
                              hipStream_t stream) {
  const float* q  = (const float*)d_in[0];
  const float* k  = (const float*)d_in[1];
  const float* v  = (const float*)d_in[2];
  const float* WQ = (const float*)d_in[3];
  const float* bQ = (const float*)d_in[4];
  const float* WK = (const float*)d_in[5];
  const float* bK = (const float*)d_in[6];
  const float* WV = (const float*)d_in[7];
  const float* bV = (const float*)d_in[8];
  const float* WO = (const float*)d_in[9];
  const float* bO = (const float*)d_in[10];
  float* out = (float*)d_out;

  const size_t plane = (size_t)BATCH * NHEAD * L_SEQ * DHEAD;  // 1,048,576 ush
  unsigned short* Qs  = (unsigned short*)d_ws;
  unsigned short* Ks  = Qs + plane;
  unsigned short* Vt  = Ks + plane;
  unsigned short* ctx = Vt + plane;                 // kept in layout; unused
  float* Opart  = (float*)(ctx + plane);            // 2048 slots x 64 x 32 f32
  float* MLpart = Opart + (size_t)2048 * 2048;      // 2048 slots x 64 x 2 f32

  hipLaunchKernelGGL(proj_kernel, dim3(64, 2, 3), dim3(256), 0, stream,
                     q, k, v, WQ, bQ, WK, bK, WV, bV, Qs, Ks, Vt);
  hipLaunchKernelGGL(attn_kernel, dim3(16, 64), dim3(256), 0, stream,
                     Qs, Ks, Vt, Opart, MLpart);
  hipLaunchKernelGGL(oproj_fused_kernel, dim3(128, 2), dim3(256), 0, stream,
                     Opart, MLpart, WO, bO, out);
}